// Round 2
// baseline (626.811 us; speedup 1.0000x reference)
//
#include <hip/hip_runtime.h>
#include <hip/hip_bf16.h>
#include <cstdint>
#include <cstddef>

// Problem constants: B=128, H=1024, L=256, N=64
typedef __bf16 bf16x8 __attribute__((ext_vector_type(8)));
typedef float  f32x4  __attribute__((ext_vector_type(4)));

__device__ __forceinline__ unsigned short f2bf(float f) {
    unsigned u = __builtin_bit_cast(unsigned, f);
    u += 0x7fffu + ((u >> 16) & 1u);          // RNE
    return (unsigned short)(u >> 16);
}

__device__ __forceinline__ float gelu_tanh(float x) {
    // jax.nn.gelu default (approximate=True)
    float z = 0.7978845608028654f * (x + 0.044715f * x * x * x);
    float e = __expf(2.0f * z);
    float t = 1.0f - 2.0f / (e + 1.0f);       // tanh(z)
    return 0.5f * x * (1.0f + t);
}

// ---------------- K1: S4D kernel k[h][t]  (H blocks x 256 threads) -------------
__global__ void k_kernel(const float* __restrict__ log_dt,
                         const float* __restrict__ arl,
                         const float* __restrict__ aim,
                         const float* __restrict__ cre,
                         const float* __restrict__ cim,
                         float* __restrict__ kout) {
    __shared__ float sRe[64], sIm[64], sCr[64], sCi[64];
    const int h = blockIdx.x;
    const int t = threadIdx.x;
    if (t < 64) {
        float dt  = expf(log_dt[h]);
        float ar  = -expf(arl[h * 64 + t]);
        float ai  = aim[h * 64 + t];
        float dre = ar * dt, dim = ai * dt;
        float er  = expf(dre);
        float s, c;
        sincosf(dim, &s, &c);
        float em1r = er * c - 1.0f, em1i = er * s;   // exp(dtA)-1
        float cr = cre[h * 64 + t], ci = cim[h * 64 + t];
        float pr = cr * em1r - ci * em1i;            // C*(exp(dtA)-1)
        float pi = cr * em1i + ci * em1r;
        float inv = 1.0f / (ar * ar + ai * ai);      // /A = *conj(A)/|A|^2
        sCr[t] = (pr * ar + pi * ai) * inv;
        sCi[t] = (pi * ar - pr * ai) * inv;
        sRe[t] = dre; sIm[t] = dim;
    }
    __syncthreads();
    float acc = 0.0f;
    const float tf = (float)t;
    #pragma unroll 8
    for (int n = 0; n < 64; n++) {
        float er = expf(sRe[n] * tf);
        float s, c;
        sincosf(sIm[n] * tf, &s, &c);
        acc += sCr[n] * er * c - sCi[n] * er * s;    // Re(C_disc * exp(dtA*t))
    }
    kout[h * 256 + t] = 2.0f * acc;
}

// ---------------- K1b: pack W_out (2H x H fp32) -> bf16, GLU pairs 16-interleaved
// packed row p: rt=p>>7, r=p&127, t16=r>>4, r16=r&15
//   t16 even -> a-row    g = rt*64 + (t16>>1)*16 + r16
//   t16 odd  -> gate-row g = 1024 + rt*64 + (t16>>1)*16 + r16
__global__ void pack_w(const float* __restrict__ W, unsigned short* __restrict__ Wp) {
    const int p   = blockIdx.x;                // 0..2047
    const int rt  = p >> 7, r = p & 127;
    const int t16 = r >> 4, r16 = r & 15;
    const int g   = ((t16 & 1) ? 1024 : 0) + rt * 64 + (t16 >> 1) * 16 + r16;
    const int t   = threadIdx.x;               // 0..255
    const float4 v = *(const float4*)(W + (size_t)g * 1024 + t * 4);
    ushort4 o;
    o.x = f2bf(v.x); o.y = f2bf(v.y); o.z = f2bf(v.z); o.w = f2bf(v.w);
    *(ushort4*)(Wp + (size_t)p * 1024 + t * 4) = o;
}

// ---------------- K2: causal conv + skip + gelu -> y_t[b][l][h] bf16 -----------
// grid (H/16, B), 256 threads. LDS: x_t[256][17], k_t[256][17] fp32 (34 KB -> 4 blk/CU).
#define CS 17
__global__ __launch_bounds__(256) void conv_kernel(
                            const float* __restrict__ x,
                            const float* __restrict__ kg,
                            const float* __restrict__ D,
                            unsigned short* __restrict__ yt) {
    __shared__ float xt[256 * CS];
    __shared__ float kt[256 * CS];
    const int b     = blockIdx.y;
    const int hbase = blockIdx.x * 16;
    const int tid   = threadIdx.x;

    // fill LDS transposed: [l][h] (pad 17 -> conflict-lite)
    {
        const int h  = tid & 15;
        const int c0 = tid >> 4;               // 0..15
        #pragma unroll
        for (int t8 = 0; t8 < 4; t8++) {
            int c4 = c0 + t8 * 16;             // float4 chunk 0..63
            float4 xv = *(const float4*)(x + (((size_t)(b * 1024 + hbase + h)) << 8) + c4 * 4);
            float4 kv = *(const float4*)(kg + (((size_t)(hbase + h)) << 8) + c4 * 4);
            int l = c4 * 4;
            xt[(l + 0) * CS + h] = xv.x; xt[(l + 1) * CS + h] = xv.y;
            xt[(l + 2) * CS + h] = xv.z; xt[(l + 3) * CS + h] = xv.w;
            kt[(l + 0) * CS + h] = kv.x; kt[(l + 1) * CS + h] = kv.y;
            kt[(l + 2) * CS + h] = kv.z; kt[(l + 3) * CS + h] = kv.w;
        }
    }
    __syncthreads();

    const int h    = tid & 15;                 // channel within group
    const int slot = tid >> 4;                 // 0..15
    const float Dh = D[hbase + h];
    // balanced: trips per thread = slot + (31-slot) = 31 uniform
    int cs2[2] = { slot, 31 - slot };

    for (int ci = 0; ci < 2; ci++) {
        const int c  = cs2[ci];
        const int l0 = c * 8;                  // output chunk [l0, l0+8)
        float acc[8];
        #pragma unroll
        for (int i = 0; i < 8; i++) acc[i] = 0.0f;
        float kw[16];                          // kw[v] = k[base-8+v]
        #pragma unroll
        for (int v = 0; v < 8; v++) kw[8 + v] = kt[(l0 + v) * CS + h];
        float X[8];
        for (int base = l0; base > 0; base -= 8) {
            #pragma unroll
            for (int v = 0; v < 8; v++) kw[v] = kt[(base - 8 + v) * CS + h];
            const int jb = l0 - base;
            #pragma unroll
            for (int u = 0; u < 8; u++) X[u] = xt[(jb + u) * CS + h];
            #pragma unroll
            for (int u = 0; u < 8; u++)
                #pragma unroll
                for (int i = 0; i < 8; i++)
                    acc[i] = fmaf(kw[8 + i - u], X[u], acc[i]);   // k[base+i-u]*x[jb+u]
            #pragma unroll
            for (int v = 0; v < 8; v++) kw[8 + v] = kw[v];
        }
        // final block base==0: k[t<0] = 0 -> triangular
        #pragma unroll
        for (int u = 0; u < 8; u++) X[u] = xt[(l0 + u) * CS + h];
        #pragma unroll
        for (int u = 0; u < 8; u++)
            #pragma unroll
            for (int i = u; i < 8; i++)
                acc[i] = fmaf(kw[8 + i - u], X[u], acc[i]);
        // skip + gelu + bf16 store
        #pragma unroll
        for (int i = 0; i < 8; i++) {
            float y = acc[i] + Dh * X[i];      // X[i] = x[l0+i]
            yt[(((size_t)(b * 256 + l0 + i)) << 10) + hbase + h] = f2bf(gelu_tanh(y));
        }
    }
}

// ---------------- K3: m97-style 128x128 bf16 MFMA GEMM + bias + GLU ------------
// A = yt (32768 x 1024 row-major bf16), B = Wp (2048 x 1024 row-major, N x K)
// grid (16 n-tiles, 256 m-tiles), 256 thr = 4 waves (2x2), wave = 64x64 (4x4 frags)
__global__ __launch_bounds__(256, 2)
void gemm_glu(const unsigned short* __restrict__ yt,
              const unsigned short* __restrict__ Wp,
              const float* __restrict__ bo,
              float* __restrict__ out) {
    __shared__ __align__(16) unsigned char smem[16384];
    unsigned char* sA = smem;                  // [k8][r] 128r x 32k bf16, 16B units
    unsigned char* sB = smem + 8192;           // [k8][p] 128p x 32k bf16
    const int bn  = blockIdx.x;                // 0..15  n-tile (128 packed cols)
    const int mt  = blockIdx.y;                // 0..255 m-tile (128 (b,l) rows)
    const int tid = threadIdx.x;
    const int w = tid >> 6, lane = tid & 63, m = lane & 15, q4 = lane >> 4;
    const int wr = w & 1, wc = w >> 1;         // wave row/col half

    f32x4 acc[4][4];
    #pragma unroll
    for (int fr = 0; fr < 4; fr++)
        #pragma unroll
        for (int fc = 0; fc < 4; fc++) acc[fr][fc] = (f32x4){0.f, 0.f, 0.f, 0.f};

    const size_t abase = ((size_t)mt) << 17;           // mt*128*1024
    const size_t wbase = ((size_t)bn) << 17;           // bn*128*1024

    for (int k0 = 0; k0 < 1024; k0 += 32) {
        #pragma unroll
        for (int t8 = 0; t8 < 2; t8++) {               // A: 512 16B chunks
            int q = t8 * 256 + tid;
            int k8 = q >> 7, r = q & 127;
            const unsigned short* gp = yt + abase + (size_t)r * 1024 + k0 + k8 * 8;
            __builtin_amdgcn_global_load_lds((const __attribute__((address_space(1))) void*)gp,
                                             (__attribute__((address_space(3))) void*)(sA + q * 16),
                                             16, 0, 0);
        }
        #pragma unroll
        for (int t8 = 0; t8 < 2; t8++) {               // B: 512 16B chunks
            int q = t8 * 256 + tid;
            int k8 = q >> 7, p = q & 127;
            const unsigned short* gp = Wp + wbase + (size_t)p * 1024 + k0 + k8 * 8;
            __builtin_amdgcn_global_load_lds((const __attribute__((address_space(1))) void*)gp,
                                             (__attribute__((address_space(3))) void*)(sB + q * 16),
                                             16, 0, 0);
        }
        __builtin_amdgcn_s_waitcnt(0x0f70);            // vmcnt(0)
        __syncthreads();

        bf16x8 aF[4];
        #pragma unroll
        for (int fr = 0; fr < 4; fr++)
            aF[fr] = *(const bf16x8*)(sA + ((q4 * 128 + wr * 64 + fr * 16 + m) << 4));
        #pragma unroll
        for (int fc = 0; fc < 4; fc++) {
            bf16x8 bF = *(const bf16x8*)(sB + ((q4 * 128 + wc * 64 + fc * 16 + m) << 4));
            #pragma unroll
            for (int fr = 0; fr < 4; fr++)
                acc[fr][fc] = __builtin_amdgcn_mfma_f32_16x16x32_bf16(aF[fr], bF, acc[fr][fc], 0, 0, 0);
        }
        __syncthreads();
    }

    // epilogue: GLU pairs: local fc even = a, fc odd = gate, same 16-col group
    // out idx = b*262144 + g*256 + l ; row = mt*128 + wr*64 + fr*16 + q4*4 + rg
    #pragma unroll
    for (int pg = 0; pg < 2; pg++) {
        const int g   = bn * 64 + (wc * 2 + pg) * 16 + m;
        const float boa = bo[g];
        const float bog = bo[1024 + g];
        #pragma unroll
        for (int fr = 0; fr < 4; fr++) {
            const int row = mt * 128 + wr * 64 + fr * 16 + q4 * 4;
            const int b   = row >> 8;
            const int l   = row & 255;
            f32x4 v;
            #pragma unroll
            for (int rg = 0; rg < 4; rg++) {
                float av = acc[fr][2 * pg][rg] + boa;
                float gv = acc[fr][2 * pg + 1][rg] + bog;
                v[rg] = av / (1.0f + __expf(-gv));
            }
            *(f32x4*)(out + (size_t)b * 262144 + (size_t)g * 256 + l) = v;
        }
    }
}

extern "C" void kernel_launch(void* const* d_in, const int* in_sizes, int n_in,
                              void* d_out, int out_size, void* d_ws, size_t ws_size,
                              hipStream_t stream) {
    const float* x   = (const float*)d_in[0];
    const float* ldt = (const float*)d_in[1];
    const float* arl = (const float*)d_in[2];
    const float* aim = (const float*)d_in[3];
    const float* cre = (const float*)d_in[4];
    const float* cim = (const float*)d_in[5];
    const float* D   = (const float*)d_in[6];
    const float* Wo  = (const float*)d_in[7];
    const float* bo  = (const float*)d_in[8];
    float* out = (float*)d_out;

    const size_t kOff = 0;                         // H*L fp32     = 1 MB
    const size_t wOff = (size_t)1 << 20;           // 2H*H bf16    = 4 MB
    const size_t yOff = wOff + ((size_t)1 << 22);  // B*L*H bf16   = 64 MB
    const size_t need = yOff + (size_t)128 * 256 * 1024 * 2;
    if (ws_size < need) return;                    // loud failure, no corruption

    float*          kg = (float*)((char*)d_ws + kOff);
    unsigned short* Wp = (unsigned short*)((char*)d_ws + wOff);
    unsigned short* yt = (unsigned short*)((char*)d_ws + yOff);

    k_kernel   <<<1024, 256, 0, stream>>>(ldt, arl, aim, cre, cim, kg);
    pack_w     <<<2048, 256, 0, stream>>>(Wo, Wp);
    conv_kernel<<<dim3(64, 128), 256, 0, stream>>>(x, kg, D, yt);
    gemm_glu   <<<dim3(16, 256), 256, 0, stream>>>(yt, Wp, bo, out);
}